// Round 8
// baseline (82.459 us; speedup 1.0000x reference)
//
#include <hip/hip_runtime.h>
#include <hip/hip_bf16.h>

// MaskedChamferDistance: B=64, NV=4096, NL=128, D=256, fp32 in/out.
// Round 8: r6 proven core + chunk-0 V-preload (r7 idea) WITHOUT the r7 lambda.
// r7's +26us was acc[8] escaping by reference into a lambda -> scratch for all
// 4 chunks (rule #20). Epilogue is now a textual macro; all indices constant.

#define NB 64
#define NVC 4096
#define NLC 128
#define ND 256
#define LDV 264   // bf16 elems per LDS row (16B-aligned rows)

using bf16x8 = __attribute__((ext_vector_type(8))) short;
using f32x4  = __attribute__((ext_vector_type(4))) float;

__device__ __forceinline__ unsigned short f2b(float f) {
  unsigned int u = __float_as_uint(f);
  u += 0x7FFFu + ((u >> 16) & 1u);          // round-to-nearest-even
  return (unsigned short)(u >> 16);
}
__device__ __forceinline__ bf16x8 pack8(float4 x, float4 y) {
  bf16x8 r;
  r[0] = (short)f2b(x.x); r[1] = (short)f2b(x.y);
  r[2] = (short)f2b(x.z); r[3] = (short)f2b(x.w);
  r[4] = (short)f2b(y.x); r[5] = (short)f2b(y.y);
  r[6] = (short)f2b(y.z); r[7] = (short)f2b(y.w);
  return r;
}

// Chunk epilogue, textually inlined (NO lambda: acc must stay in registers).
#define EPILOGUE(vbase_, n0_, acc_)                                        \
  do {                                                                     \
    float nn = (n0_);                                                      \
    nn += __shfl_xor(nn, 16);                                              \
    nn += __shfl_xor(nn, 32);                                              \
    const float mk_l = mask[(size_t)b * NVC + (vbase_) + llo];             \
    float av[4], mkv[4];                                                   \
    _Pragma("unroll")                                                      \
    for (int r = 0; r < 4; ++r) {                                          \
      av[r] = __shfl(nn, lhi * 4 + r);                                     \
      mkv[r] = __shfl(mk_l, lhi * 4 + r);                                  \
    }                                                                      \
    _Pragma("unroll")                                                      \
    for (int r = 0; r < 4; ++r) {                                          \
      float v = bncol[0] - 2.f * acc_[0][r];                               \
      _Pragma("unroll")                                                    \
      for (int n = 1; n < 8; ++n)                                          \
        v = fminf(v, bncol[n] - 2.f * acc_[n][r]);                         \
      v = fminf(v, __shfl_xor(v, 1));                                      \
      v = fminf(v, __shfl_xor(v, 2));                                      \
      v = fminf(v, __shfl_xor(v, 4));                                      \
      v = fminf(v, __shfl_xor(v, 8));                                      \
      if (llo == 0 && mkv[r] != 0.f) { rs += av[r] + v; msum += 1.f; }     \
    }                                                                      \
    _Pragma("unroll")                                                      \
    for (int n = 0; n < 8; ++n) {                                          \
      float v = cmin[n];                                                   \
      _Pragma("unroll")                                                    \
      for (int r = 0; r < 4; ++r) {                                        \
        const float s = av[r] - 2.f * acc_[n][r];                          \
        v = fminf(v, (mkv[r] != 0.f) ? s : 3.0e38f);                       \
      }                                                                    \
      cmin[n] = v;                                                         \
    }                                                                      \
  } while (0)

// ---- main: 512 persistent blocks (2/CU); block = (batch b, 512-row slice).
//      Chunk-0 A-fragments preloaded before L-stage (V streams from t=0) ----
__global__ __launch_bounds__(512, 4) void chamfer_main(
    const float* __restrict__ vf, const float* __restrict__ lf,
    const float* __restrict__ mask,
    float* __restrict__ colmin_part, float* __restrict__ rowsum_part,
    float* __restrict__ nv_part)
{
  __shared__ __attribute__((aligned(16))) unsigned short Llds[NLC * LDV];
  __shared__ float bn_lds[NLC];
  __shared__ float colmin_s[8][NLC];
  __shared__ float rowsum_s[8];
  __shared__ float msum_s[8];

  const int t = threadIdx.x, wid = t >> 6, lane = t & 63;
  // XCD-clustering swizzle (bijective over 512): slices of a batch share an XCD
  const int orig = blockIdx.x;
  const int b = (orig & 7) * 8 + (orig >> 6);
  const int slice = (orig >> 3) & 7;
  const int llo = lane & 15, lhi = lane >> 4;

  // ---- preload chunk-0 A-fragments (independent of L; straight-line) ----
  const int vbase0 = slice * 512 + wid * 16;
  bf16x8 afr0[8];
  float pn0 = 0.f;
  {
    const float* arow = vf + ((size_t)b * NVC + vbase0 + llo) * ND + lhi * 8;
    #pragma unroll
    for (int kk = 0; kk < 8; ++kk) {
      float4 a00 = *reinterpret_cast<const float4*>(arow + kk * 32);
      float4 a01 = *reinterpret_cast<const float4*>(arow + kk * 32 + 4);
      pn0 += a00.x*a00.x + a00.y*a00.y + a00.z*a00.z + a00.w*a00.w
           + a01.x*a01.x + a01.y*a01.y + a01.z*a01.z + a01.w*a01.w;
      afr0[kk] = pack8(a00, a01);
    }
  }

  // ---- stage L (128 x 256) fp32 -> bf16 LDS; |L|^2 row norms in-flight ----
  {
    const int row = t >> 2, c4 = t & 3;    // 4 lanes per row, 16 float4 each
    const float* src = lf + ((size_t)b * NLC + row) * ND;
    float nrm = 0.f;
    #pragma unroll
    for (int i = 0; i < 16; ++i) {
      const int col = (c4 + 4 * i) * 4;
      float4 v = *reinterpret_cast<const float4*>(src + col);
      nrm += v.x * v.x + v.y * v.y + v.z * v.z + v.w * v.w;
      ushort4 h;
      h.x = f2b(v.x); h.y = f2b(v.y); h.z = f2b(v.z); h.w = f2b(v.w);
      *reinterpret_cast<ushort4*>(&Llds[row * LDV + col]) = h;
    }
    nrm += __shfl_xor(nrm, 1);
    nrm += __shfl_xor(nrm, 2);
    if (c4 == 0) bn_lds[row] = nrm;
  }
  __syncthreads();

  float bncol[8];
  #pragma unroll
  for (int n = 0; n < 8; ++n) bncol[n] = bn_lds[n * 16 + llo];

  const int bbase = llo * LDV + lhi * 8;

  float cmin[8];
  #pragma unroll
  for (int n = 0; n < 8; ++n) cmin[n] = 3.0e38f;
  float rs = 0.f, msum = 0.f;

  // ---- chunk 0 (peeled: MFMA from preloaded registers) ----
  {
    f32x4 acc[8];
    #pragma unroll
    for (int n = 0; n < 8; ++n) acc[n] = (f32x4){0.f, 0.f, 0.f, 0.f};
    #pragma unroll
    for (int kk = 0; kk < 8; ++kk) {
      const int ko = kk * 32;
      #pragma unroll
      for (int n = 0; n < 8; ++n) {
        bf16x8 bfr = *reinterpret_cast<const bf16x8*>(&Llds[bbase + n * 16 * LDV + ko]);
        acc[n] = __builtin_amdgcn_mfma_f32_16x16x32_bf16(afr0[kk], bfr, acc[n], 0, 0, 0);
      }
    }
    EPILOGUE(vbase0, pn0, acc);
  }

  // ---- chunks 1..3 (r6 steady state, compiler-scheduled) ----
  for (int c = 1; c < 4; ++c) {
    const int vbase = slice * 512 + c * 128 + wid * 16;
    const float* arow = vf + ((size_t)b * NVC + vbase + llo) * ND + lhi * 8;

    f32x4 acc[8];
    #pragma unroll
    for (int n = 0; n < 8; ++n) acc[n] = (f32x4){0.f, 0.f, 0.f, 0.f};
    float n0 = 0.f;

    #pragma unroll 2
    for (int kk = 0; kk < 8; ++kk) {
      const int ko = kk * 32;
      float4 a00 = *reinterpret_cast<const float4*>(arow + ko);
      float4 a01 = *reinterpret_cast<const float4*>(arow + ko + 4);
      n0 += a00.x*a00.x + a00.y*a00.y + a00.z*a00.z + a00.w*a00.w
          + a01.x*a01.x + a01.y*a01.y + a01.z*a01.z + a01.w*a01.w;
      bf16x8 af0 = pack8(a00, a01);
      #pragma unroll
      for (int n = 0; n < 8; ++n) {
        bf16x8 bfr = *reinterpret_cast<const bf16x8*>(&Llds[bbase + n * 16 * LDV + ko]);
        acc[n] = __builtin_amdgcn_mfma_f32_16x16x32_bf16(af0, bfr, acc[n], 0, 0, 0);
      }
    }

    EPILOGUE(vbase, n0, acc);
  }

  // ---- wave-level finishes ----
  rs += __shfl_xor(rs, 16);     rs += __shfl_xor(rs, 32);
  msum += __shfl_xor(msum, 16); msum += __shfl_xor(msum, 32);
  #pragma unroll
  for (int n = 0; n < 8; ++n) {
    float v = cmin[n];
    v = fminf(v, __shfl_xor(v, 16));
    v = fminf(v, __shfl_xor(v, 32));
    if (lhi == 0) colmin_s[wid][n * 16 + llo] = v;
  }
  if (lane == 0) { rowsum_s[wid] = rs; msum_s[wid] = msum; }
  __syncthreads();

  const size_t pidx = (size_t)b * 8 + slice;
  if (t < NLC) {
    float cm = colmin_s[0][t];
    #pragma unroll
    for (int w = 1; w < 8; ++w) cm = fminf(cm, colmin_s[w][t]);
    colmin_part[pidx * NLC + t] = cm + bn_lds[t];   // fold +|L|^2 here
  }
  if (t == 0) {
    float r2 = 0.f, m2 = 0.f;
    #pragma unroll
    for (int w = 0; w < 8; ++w) { r2 += rowsum_s[w]; m2 += msum_s[w]; }
    rowsum_part[pidx] = r2;
    nv_part[pidx] = m2;
  }
}

// ---- fin: reduce 8 partials per batch; out[b] ----
__global__ __launch_bounds__(128) void chamfer_fin(
    const float* __restrict__ colmin_part, const float* __restrict__ rowsum_part,
    const float* __restrict__ nv_part, float* __restrict__ out)
{
  const int b = blockIdx.x, t = threadIdx.x;
  __shared__ float red[2];
  float cm = 3.0e38f;
  #pragma unroll
  for (int p = 0; p < 8; ++p)
    cm = fminf(cm, colmin_part[((size_t)b * 8 + p) * NLC + t]);
  float cs = cm;
  #pragma unroll
  for (int off = 32; off >= 1; off >>= 1) cs += __shfl_xor(cs, off);
  if ((t & 63) == 0) red[t >> 6] = cs;
  __syncthreads();
  if (t == 0) {
    float rsum = 0.f, nv = 0.f;
    #pragma unroll
    for (int p = 0; p < 8; ++p) {
      rsum += rowsum_part[(size_t)b * 8 + p];
      nv   += nv_part[(size_t)b * 8 + p];
    }
    out[b] = (red[0] + red[1]) / (float)NLC + rsum / nv;
  }
}

extern "C" void kernel_launch(void* const* d_in, const int* in_sizes, int n_in,
                              void* d_out, int out_size, void* d_ws, size_t ws_size,
                              hipStream_t stream) {
  const float* vf   = (const float*)d_in[0];
  const float* lf   = (const float*)d_in[1];
  const float* mask = (const float*)d_in[2];
  float* out = (float*)d_out;

  char* ws = (char*)d_ws;
  float* colmin_part = (float*)ws;                          // 64*8*128*4 = 256 KB
  size_t off = (size_t)NB * 8 * NLC * sizeof(float);
  float* rowsum_part = (float*)(ws + off);                  // 2 KB
  off += (size_t)NB * 8 * sizeof(float);
  float* nv_part = (float*)(ws + off);                      // 2 KB

  chamfer_main<<<dim3(NB * 8), dim3(512), 0, stream>>>(vf, lf, mask,
                                                       colmin_part, rowsum_part, nv_part);
  chamfer_fin<<<dim3(NB), dim3(128), 0, stream>>>(colmin_part, rowsum_part, nv_part, out);
}

// Round 9
// 55.184 us; speedup vs baseline: 1.4942x; 1.4942x over previous
//
#include <hip/hip_runtime.h>
#include <hip/hip_bf16.h>

// MaskedChamferDistance: B=64, NV=4096, NL=128, D=256, fp32 in/out.
// Round 9: r6 per-wave code verbatim; geometry change only. 1024-thr blocks,
// grid=256 (exactly 1 block/CU): per-CU L-stage bubble halves, 4 partials per
// batch, uniform residency. No preload (r7/r8: spills), no lambda (r5/r7).

#define NB 64
#define NVC 4096
#define NLC 128
#define ND 256
#define LDV 264   // bf16 elems per LDS row (16B-aligned rows)

using bf16x8 = __attribute__((ext_vector_type(8))) short;
using f32x4  = __attribute__((ext_vector_type(4))) float;

__device__ __forceinline__ unsigned short f2b(float f) {
  unsigned int u = __float_as_uint(f);
  u += 0x7FFFu + ((u >> 16) & 1u);          // round-to-nearest-even
  return (unsigned short)(u >> 16);
}
__device__ __forceinline__ bf16x8 pack8(float4 x, float4 y) {
  bf16x8 r;
  r[0] = (short)f2b(x.x); r[1] = (short)f2b(x.y);
  r[2] = (short)f2b(x.z); r[3] = (short)f2b(x.w);
  r[4] = (short)f2b(y.x); r[5] = (short)f2b(y.y);
  r[6] = (short)f2b(y.z); r[7] = (short)f2b(y.w);
  return r;
}

// ---- main: 256 blocks x 1024 thr (1/CU); block = (batch b, 1024-row slice).
//      Stages L fp32->bf16 LDS; 4 chunks of 256 V-rows (16 waves x 16 rows) ----
__global__ __launch_bounds__(1024, 4) void chamfer_main(
    const float* __restrict__ vf, const float* __restrict__ lf,
    const float* __restrict__ mask,
    float* __restrict__ colmin_part, float* __restrict__ rowsum_part,
    float* __restrict__ nv_part)
{
  __shared__ __attribute__((aligned(16))) unsigned short Llds[NLC * LDV];
  __shared__ float bn_lds[NLC];
  __shared__ float colmin_s[16][NLC];
  __shared__ float rowsum_s[16];
  __shared__ float msum_s[16];

  const int t = threadIdx.x, wid = t >> 6, lane = t & 63;
  // XCD-clustering swizzle (bijective over 256): 4 slices of a batch on one XCD
  const int orig = blockIdx.x;
  const int xcd = orig & 7, idx = orig >> 3;        // idx in [0,32)
  const int slice = idx & 3;                        // 4 slices of 1024 rows
  const int b = xcd * 8 + (idx >> 2);               // 8 batches per XCD
  const int llo = lane & 15, lhi = lane >> 4;

  // ---- stage L (128 x 256) fp32 -> bf16 LDS; |L|^2 row norms in-flight ----
  {
    const int row = t >> 3, c8 = t & 7;    // 8 lanes per row, 8 float4 each
    const float* src = lf + ((size_t)b * NLC + row) * ND;
    float nrm = 0.f;
    #pragma unroll
    for (int i = 0; i < 8; ++i) {
      const int col = (c8 + 8 * i) * 4;
      float4 v = *reinterpret_cast<const float4*>(src + col);
      nrm += v.x * v.x + v.y * v.y + v.z * v.z + v.w * v.w;
      ushort4 h;
      h.x = f2b(v.x); h.y = f2b(v.y); h.z = f2b(v.z); h.w = f2b(v.w);
      *reinterpret_cast<ushort4*>(&Llds[row * LDV + col]) = h;
    }
    nrm += __shfl_xor(nrm, 1);
    nrm += __shfl_xor(nrm, 2);
    nrm += __shfl_xor(nrm, 4);
    if (c8 == 0) bn_lds[row] = nrm;
  }
  __syncthreads();

  float bncol[8];
  #pragma unroll
  for (int n = 0; n < 8; ++n) bncol[n] = bn_lds[n * 16 + llo];

  const int bbase = llo * LDV + lhi * 8;

  float cmin[8];
  #pragma unroll
  for (int n = 0; n < 8; ++n) cmin[n] = 3.0e38f;
  float rs = 0.f, msum = 0.f;

  for (int c = 0; c < 4; ++c) {
    const int vbase = slice * 1024 + c * 256 + wid * 16;
    const float* arow = vf + ((size_t)b * NVC + vbase + llo) * ND + lhi * 8;

    f32x4 acc[8];
    #pragma unroll
    for (int n = 0; n < 8; ++n) acc[n] = (f32x4){0.f, 0.f, 0.f, 0.f};
    float n0 = 0.f;

    #pragma unroll 2
    for (int kk = 0; kk < 8; ++kk) {
      const int ko = kk * 32;
      float4 a00 = *reinterpret_cast<const float4*>(arow + ko);
      float4 a01 = *reinterpret_cast<const float4*>(arow + ko + 4);
      n0 += a00.x*a00.x + a00.y*a00.y + a00.z*a00.z + a00.w*a00.w
          + a01.x*a01.x + a01.y*a01.y + a01.z*a01.z + a01.w*a01.w;
      bf16x8 af0 = pack8(a00, a01);
      #pragma unroll
      for (int n = 0; n < 8; ++n) {
        bf16x8 bfr = *reinterpret_cast<const bf16x8*>(&Llds[bbase + n * 16 * LDV + ko]);
        acc[n] = __builtin_amdgcn_mfma_f32_16x16x32_bf16(af0, bfr, acc[n], 0, 0, 0);
      }
    }

    // complete row norms across 4 lhi k-chunks
    n0 += __shfl_xor(n0, 16);
    n0 += __shfl_xor(n0, 32);

    // redistribute to C-layout rows: row = lhi*4 + r
    const float mk_l = mask[(size_t)b * NVC + vbase + llo];
    float av[4], mk[4];
    #pragma unroll
    for (int r = 0; r < 4; ++r) {
      av[r] = __shfl(n0, lhi * 4 + r);
      mk[r] = __shfl(mk_l, lhi * 4 + r);
    }

    // row mins (wave covers all 128 cols) + masked row-sum + mask count
    #pragma unroll
    for (int r = 0; r < 4; ++r) {
      float v = bncol[0] - 2.f * acc[0][r];
      #pragma unroll
      for (int n = 1; n < 8; ++n)
        v = fminf(v, bncol[n] - 2.f * acc[n][r]);
      v = fminf(v, __shfl_xor(v, 1));
      v = fminf(v, __shfl_xor(v, 2));
      v = fminf(v, __shfl_xor(v, 4));
      v = fminf(v, __shfl_xor(v, 8));
      if (llo == 0 && mk[r] != 0.f) { rs += av[r] + v; msum += 1.f; }
    }

    // col mins over this chunk's 16 rows (valid rows only), in-lane accumulate
    #pragma unroll
    for (int n = 0; n < 8; ++n) {
      float v = cmin[n];
      #pragma unroll
      for (int r = 0; r < 4; ++r) {
        const float s = av[r] - 2.f * acc[n][r];
        v = fminf(v, (mk[r] != 0.f) ? s : 3.0e38f);
      }
      cmin[n] = v;
    }
  }

  // ---- wave-level finishes ----
  rs += __shfl_xor(rs, 16);     rs += __shfl_xor(rs, 32);
  msum += __shfl_xor(msum, 16); msum += __shfl_xor(msum, 32);
  #pragma unroll
  for (int n = 0; n < 8; ++n) {
    float v = cmin[n];
    v = fminf(v, __shfl_xor(v, 16));
    v = fminf(v, __shfl_xor(v, 32));
    if (lhi == 0) colmin_s[wid][n * 16 + llo] = v;
  }
  if (lane == 0) { rowsum_s[wid] = rs; msum_s[wid] = msum; }
  __syncthreads();

  const size_t pidx = (size_t)b * 4 + slice;
  if (t < NLC) {
    float cm = colmin_s[0][t];
    #pragma unroll
    for (int w = 1; w < 16; ++w) cm = fminf(cm, colmin_s[w][t]);
    colmin_part[pidx * NLC + t] = cm + bn_lds[t];   // fold +|L|^2 here
  }
  if (t == 0) {
    float r2 = 0.f, m2 = 0.f;
    #pragma unroll
    for (int w = 0; w < 16; ++w) { r2 += rowsum_s[w]; m2 += msum_s[w]; }
    rowsum_part[pidx] = r2;
    nv_part[pidx] = m2;
  }
}

// ---- fin: reduce 4 partials per batch; out[b] ----
__global__ __launch_bounds__(128) void chamfer_fin(
    const float* __restrict__ colmin_part, const float* __restrict__ rowsum_part,
    const float* __restrict__ nv_part, float* __restrict__ out)
{
  const int b = blockIdx.x, t = threadIdx.x;
  __shared__ float red[2];
  float cm = 3.0e38f;
  #pragma unroll
  for (int p = 0; p < 4; ++p)
    cm = fminf(cm, colmin_part[((size_t)b * 4 + p) * NLC + t]);
  float cs = cm;
  #pragma unroll
  for (int off = 32; off >= 1; off >>= 1) cs += __shfl_xor(cs, off);
  if ((t & 63) == 0) red[t >> 6] = cs;
  __syncthreads();
  if (t == 0) {
    float rsum = 0.f, nv = 0.f;
    #pragma unroll
    for (int p = 0; p < 4; ++p) {
      rsum += rowsum_part[(size_t)b * 4 + p];
      nv   += nv_part[(size_t)b * 4 + p];
    }
    out[b] = (red[0] + red[1]) / (float)NLC + rsum / nv;
  }
}

extern "C" void kernel_launch(void* const* d_in, const int* in_sizes, int n_in,
                              void* d_out, int out_size, void* d_ws, size_t ws_size,
                              hipStream_t stream) {
  const float* vf   = (const float*)d_in[0];
  const float* lf   = (const float*)d_in[1];
  const float* mask = (const float*)d_in[2];
  float* out = (float*)d_out;

  char* ws = (char*)d_ws;
  float* colmin_part = (float*)ws;                          // 64*4*128*4 = 128 KB
  size_t off = (size_t)NB * 4 * NLC * sizeof(float);
  float* rowsum_part = (float*)(ws + off);                  // 1 KB
  off += (size_t)NB * 4 * sizeof(float);
  float* nv_part = (float*)(ws + off);                      // 1 KB

  chamfer_main<<<dim3(256), dim3(1024), 0, stream>>>(vf, lf, mask,
                                                     colmin_part, rowsum_part, nv_part);
  chamfer_fin<<<dim3(NB), dim3(128), 0, stream>>>(colmin_part, rowsum_part, nv_part, out);
}

// Round 10
// 54.389 us; speedup vs baseline: 1.5161x; 1.0146x over previous
//
#include <hip/hip_runtime.h>
#include <hip/hip_bf16.h>

// MaskedChamferDistance: B=64, NV=4096, NL=128, D=256, fp32 in/out.
// Round 10: r6 verbatim except K-loop unroll 2 -> 4 (deeper compiler-managed
// load look-ahead; ~1760cy cover vs ~900cy HBM latency). No manual pipelining
// (r5/r7/r8 all spilled), no geometry change (r9 neutral).

#define NB 64
#define NVC 4096
#define NLC 128
#define ND 256
#define LDV 264   // bf16 elems per LDS row (16B-aligned rows)

using bf16x8 = __attribute__((ext_vector_type(8))) short;
using f32x4  = __attribute__((ext_vector_type(4))) float;

__device__ __forceinline__ unsigned short f2b(float f) {
  unsigned int u = __float_as_uint(f);
  u += 0x7FFFu + ((u >> 16) & 1u);          // round-to-nearest-even
  return (unsigned short)(u >> 16);
}
__device__ __forceinline__ bf16x8 pack8(float4 x, float4 y) {
  bf16x8 r;
  r[0] = (short)f2b(x.x); r[1] = (short)f2b(x.y);
  r[2] = (short)f2b(x.z); r[3] = (short)f2b(x.w);
  r[4] = (short)f2b(y.x); r[5] = (short)f2b(y.y);
  r[6] = (short)f2b(y.z); r[7] = (short)f2b(y.w);
  return r;
}

// ---- main: 512 persistent blocks (2/CU); block = (batch b, 512-row slice).
//      Stages L fp32->bf16 LDS itself; 4 chunks of 128 V-rows; partials out ----
__global__ __launch_bounds__(512, 4) void chamfer_main(
    const float* __restrict__ vf, const float* __restrict__ lf,
    const float* __restrict__ mask,
    float* __restrict__ colmin_part, float* __restrict__ rowsum_part,
    float* __restrict__ nv_part)
{
  __shared__ __attribute__((aligned(16))) unsigned short Llds[NLC * LDV];
  __shared__ float bn_lds[NLC];
  __shared__ float colmin_s[8][NLC];
  __shared__ float rowsum_s[8];
  __shared__ float msum_s[8];

  const int t = threadIdx.x, wid = t >> 6, lane = t & 63;
  // XCD-clustering swizzle (bijective over 512): slices of a batch share an XCD
  const int orig = blockIdx.x;
  const int b = (orig & 7) * 8 + (orig >> 6);
  const int slice = (orig >> 3) & 7;
  const int llo = lane & 15, lhi = lane >> 4;

  // ---- stage L (128 x 256) fp32 -> bf16 LDS; |L|^2 row norms in-flight ----
  {
    const int row = t >> 2, c4 = t & 3;    // 4 lanes per row, 16 float4 each
    const float* src = lf + ((size_t)b * NLC + row) * ND;
    float nrm = 0.f;
    #pragma unroll
    for (int i = 0; i < 16; ++i) {
      const int col = (c4 + 4 * i) * 4;
      float4 v = *reinterpret_cast<const float4*>(src + col);
      nrm += v.x * v.x + v.y * v.y + v.z * v.z + v.w * v.w;
      ushort4 h;
      h.x = f2b(v.x); h.y = f2b(v.y); h.z = f2b(v.z); h.w = f2b(v.w);
      *reinterpret_cast<ushort4*>(&Llds[row * LDV + col]) = h;
    }
    nrm += __shfl_xor(nrm, 1);
    nrm += __shfl_xor(nrm, 2);
    if (c4 == 0) bn_lds[row] = nrm;
  }
  __syncthreads();

  float bncol[8];
  #pragma unroll
  for (int n = 0; n < 8; ++n) bncol[n] = bn_lds[n * 16 + llo];

  const int bbase = llo * LDV + lhi * 8;

  float cmin[8];
  #pragma unroll
  for (int n = 0; n < 8; ++n) cmin[n] = 3.0e38f;
  float rs = 0.f, msum = 0.f;

  for (int c = 0; c < 4; ++c) {
    const int vbase = slice * 512 + c * 128 + wid * 16;
    const float* arow = vf + ((size_t)b * NVC + vbase + llo) * ND + lhi * 8;

    f32x4 acc[8];
    #pragma unroll
    for (int n = 0; n < 8; ++n) acc[n] = (f32x4){0.f, 0.f, 0.f, 0.f};
    float n0 = 0.f;

    #pragma unroll 4
    for (int kk = 0; kk < 8; ++kk) {
      const int ko = kk * 32;
      float4 a00 = *reinterpret_cast<const float4*>(arow + ko);
      float4 a01 = *reinterpret_cast<const float4*>(arow + ko + 4);
      n0 += a00.x*a00.x + a00.y*a00.y + a00.z*a00.z + a00.w*a00.w
          + a01.x*a01.x + a01.y*a01.y + a01.z*a01.z + a01.w*a01.w;
      bf16x8 af0 = pack8(a00, a01);
      #pragma unroll
      for (int n = 0; n < 8; ++n) {
        bf16x8 bfr = *reinterpret_cast<const bf16x8*>(&Llds[bbase + n * 16 * LDV + ko]);
        acc[n] = __builtin_amdgcn_mfma_f32_16x16x32_bf16(af0, bfr, acc[n], 0, 0, 0);
      }
    }

    // complete row norms across 4 lhi k-chunks
    n0 += __shfl_xor(n0, 16);
    n0 += __shfl_xor(n0, 32);

    // redistribute to C-layout rows: row = lhi*4 + r
    const float mk_l = mask[(size_t)b * NVC + vbase + llo];
    float av[4], mk[4];
    #pragma unroll
    for (int r = 0; r < 4; ++r) {
      av[r] = __shfl(n0, lhi * 4 + r);
      mk[r] = __shfl(mk_l, lhi * 4 + r);
    }

    // row mins (wave covers all 128 cols) + masked row-sum + mask count
    #pragma unroll
    for (int r = 0; r < 4; ++r) {
      float v = bncol[0] - 2.f * acc[0][r];
      #pragma unroll
      for (int n = 1; n < 8; ++n)
        v = fminf(v, bncol[n] - 2.f * acc[n][r]);
      v = fminf(v, __shfl_xor(v, 1));
      v = fminf(v, __shfl_xor(v, 2));
      v = fminf(v, __shfl_xor(v, 4));
      v = fminf(v, __shfl_xor(v, 8));
      if (llo == 0 && mk[r] != 0.f) { rs += av[r] + v; msum += 1.f; }
    }

    // col mins over this chunk's 16 rows (valid rows only), in-lane accumulate
    #pragma unroll
    for (int n = 0; n < 8; ++n) {
      float v = cmin[n];
      #pragma unroll
      for (int r = 0; r < 4; ++r) {
        const float s = av[r] - 2.f * acc[n][r];
        v = fminf(v, (mk[r] != 0.f) ? s : 3.0e38f);
      }
      cmin[n] = v;
    }
  }

  // ---- wave-level finishes ----
  rs += __shfl_xor(rs, 16);     rs += __shfl_xor(rs, 32);
  msum += __shfl_xor(msum, 16); msum += __shfl_xor(msum, 32);
  #pragma unroll
  for (int n = 0; n < 8; ++n) {
    float v = cmin[n];
    v = fminf(v, __shfl_xor(v, 16));
    v = fminf(v, __shfl_xor(v, 32));
    if (lhi == 0) colmin_s[wid][n * 16 + llo] = v;
  }
  if (lane == 0) { rowsum_s[wid] = rs; msum_s[wid] = msum; }
  __syncthreads();

  const size_t pidx = (size_t)b * 8 + slice;
  if (t < NLC) {
    float cm = colmin_s[0][t];
    #pragma unroll
    for (int w = 1; w < 8; ++w) cm = fminf(cm, colmin_s[w][t]);
    colmin_part[pidx * NLC + t] = cm + bn_lds[t];   // fold +|L|^2 here
  }
  if (t == 0) {
    float r2 = 0.f, m2 = 0.f;
    #pragma unroll
    for (int w = 0; w < 8; ++w) { r2 += rowsum_s[w]; m2 += msum_s[w]; }
    rowsum_part[pidx] = r2;
    nv_part[pidx] = m2;
  }
}

// ---- fin: reduce 8 partials per batch; out[b] ----
__global__ __launch_bounds__(128) void chamfer_fin(
    const float* __restrict__ colmin_part, const float* __restrict__ rowsum_part,
    const float* __restrict__ nv_part, float* __restrict__ out)
{
  const int b = blockIdx.x, t = threadIdx.x;
  __shared__ float red[2];
  float cm = 3.0e38f;
  #pragma unroll
  for (int p = 0; p < 8; ++p)
    cm = fminf(cm, colmin_part[((size_t)b * 8 + p) * NLC + t]);
  float cs = cm;
  #pragma unroll
  for (int off = 32; off >= 1; off >>= 1) cs += __shfl_xor(cs, off);
  if ((t & 63) == 0) red[t >> 6] = cs;
  __syncthreads();
  if (t == 0) {
    float rsum = 0.f, nv = 0.f;
    #pragma unroll
    for (int p = 0; p < 8; ++p) {
      rsum += rowsum_part[(size_t)b * 8 + p];
      nv   += nv_part[(size_t)b * 8 + p];
    }
    out[b] = (red[0] + red[1]) / (float)NLC + rsum / nv;
  }
}

extern "C" void kernel_launch(void* const* d_in, const int* in_sizes, int n_in,
                              void* d_out, int out_size, void* d_ws, size_t ws_size,
                              hipStream_t stream) {
  const float* vf   = (const float*)d_in[0];
  const float* lf   = (const float*)d_in[1];
  const float* mask = (const float*)d_in[2];
  float* out = (float*)d_out;

  char* ws = (char*)d_ws;
  float* colmin_part = (float*)ws;                          // 64*8*128*4 = 256 KB
  size_t off = (size_t)NB * 8 * NLC * sizeof(float);
  float* rowsum_part = (float*)(ws + off);                  // 2 KB
  off += (size_t)NB * 8 * sizeof(float);
  float* nv_part = (float*)(ws + off);                      // 2 KB

  chamfer_main<<<dim3(NB * 8), dim3(512), 0, stream>>>(vf, lf, mask,
                                                       colmin_part, rowsum_part, nv_part);
  chamfer_fin<<<dim3(NB), dim3(128), 0, stream>>>(colmin_part, rowsum_part, nv_part, out);
}